// Round 1
// baseline (435.017 us; speedup 1.0000x reference)
//
#include <hip/hip_runtime.h>

typedef unsigned int u32;
typedef __bf16 bf16;
typedef bf16 bf16x4 __attribute__((ext_vector_type(4)));
typedef bf16 bf16x8 __attribute__((ext_vector_type(8)));
typedef float f32x4 __attribute__((ext_vector_type(4)));

#define T_ 2048
#define D_ 2048
#define H_ 16
#define HD_ 128
#define SCALE_ 0.022097086912079608f  // 2048^-0.5 (full embed_dim per reference)

typedef __attribute__((address_space(1))) u32 gu32;
typedef __attribute__((address_space(3))) u32 lu32;

__device__ __forceinline__ void gload_lds16(const void* g, void* l) {
  // async global->LDS, 16B/lane; LDS dest is wave-uniform base + lane*16
  __builtin_amdgcn_global_load_lds((gu32*)(void*)g, (lu32*)l, 16, 0, 0);
}

// ---------------- cast x: fp32 -> bf16 ----------------
__global__ void cast_x_kernel(const float* __restrict__ x, bf16* __restrict__ xb) {
  int i = blockIdx.x * 256 + threadIdx.x;
  float4 v = ((const float4*)x)[i];
  bf16x4 o;
  o.x = (bf16)v.x; o.y = (bf16)v.y; o.z = (bf16)v.z; o.w = (bf16)v.w;
  ((bf16x4*)xb)[i] = o;
}

// ------- transpose+cast weights: W[k][n] fp32 -> Wt[n][k] bf16 -------
__global__ void twcast_kernel(const float* __restrict__ w0, const float* __restrict__ w1,
                              const float* __restrict__ w2, const float* __restrict__ w3,
                              bf16* __restrict__ o0, bf16* __restrict__ o1,
                              bf16* __restrict__ o2, bf16* __restrict__ o3) {
  int z = blockIdx.z;
  const float* W = (z == 0) ? w0 : (z == 1) ? w1 : (z == 2) ? w2 : w3;
  bf16* O = (z == 0) ? o0 : (z == 1) ? o1 : (z == 2) ? o2 : o3;
  __shared__ float tile[64][65];
  int t = threadIdx.x, tx = t & 15, ty = t >> 4;
  int n0 = blockIdx.x * 64, k0 = blockIdx.y * 64;
#pragma unroll
  for (int i = 0; i < 4; i++) {
    float4 v = *(const float4*)&W[(size_t)(k0 + ty + i * 16) * D_ + n0 + tx * 4];
    tile[ty + i * 16][tx * 4 + 0] = v.x;
    tile[ty + i * 16][tx * 4 + 1] = v.y;
    tile[ty + i * 16][tx * 4 + 2] = v.z;
    tile[ty + i * 16][tx * 4 + 3] = v.w;
  }
  __syncthreads();
#pragma unroll
  for (int i = 0; i < 4; i++) {
    int n = ty + i * 16;
    bf16x4 o;
    o.x = (bf16)tile[tx * 4 + 0][n];
    o.y = (bf16)tile[tx * 4 + 1][n];
    o.z = (bf16)tile[tx * 4 + 2][n];
    o.w = (bf16)tile[tx * 4 + 3][n];
    *(bf16x4*)&O[(size_t)(n0 + n) * D_ + k0 + tx * 4] = o;
  }
}

// ------- shared 128x128-tile GEMM core: C = A[M][2048] @ Bt[n][k]^T -------
// LDS tiles XOR-swizzled (byte ^= (row&7)<<4); global source pre-swizzled so
// linear global_load_lds writes land in swizzled layout (both-sides rule).
__device__ __forceinline__ void gemm_core_128(const bf16* __restrict__ A,
                                              const bf16* __restrict__ Bt,
                                              f32x4 acc[4][4], int m0, int n0) {
  __shared__ char smem[32768];
  char* aT = smem;           // [128 rows][64 k] bf16, swizzled
  char* bT = smem + 16384;   // [128 n-rows][64 k] bf16, swizzled
  const int t = threadIdx.x;
  const int lane = t & 63;
  const int wr = (t >> 7) & 1;  // wave row (wave id >> 1)
  const int wc = (t >> 6) & 1;  // wave col (wave id & 1)
  for (int k0 = 0; k0 < 2048; k0 += 64) {
    __syncthreads();  // prior compute done before overwrite
#pragma unroll
    for (int i = 0; i < 4; i++) {
      int L = i * 4096 + t * 16;
      int row = L >> 7;
      int kb = (L & 127) ^ ((row & 7) << 4);  // inverse swizzle on source
      gload_lds16(A + (size_t)(m0 + row) * 2048 + k0 + (kb >> 1), aT + L);
      gload_lds16(Bt + (size_t)(n0 + row) * 2048 + k0 + (kb >> 1), bT + L);
    }
    __syncthreads();  // compiler drains vmcnt before barrier
#pragma unroll
    for (int kk = 0; kk < 2; kk++) {
      int ak = kk * 64 + ((lane >> 4) << 4);
      bf16x8 af[4], bfv[4];
#pragma unroll
      for (int f = 0; f < 4; f++) {
        int ar = wr * 64 + f * 16 + (lane & 15);
        af[f] = *(const bf16x8*)(aT + ar * 128 + (ak ^ ((ar & 7) << 4)));
        int br = wc * 64 + f * 16 + (lane & 15);
        bfv[f] = *(const bf16x8*)(bT + br * 128 + (ak ^ ((br & 7) << 4)));
      }
#pragma unroll
      for (int mi = 0; mi < 4; mi++)
#pragma unroll
        for (int ni = 0; ni < 4; ni++)
          acc[mi][ni] = __builtin_amdgcn_mfma_f32_16x16x32_bf16(af[mi], bfv[ni], acc[mi][ni], 0, 0, 0);
    }
  }
}

// ------- QKV projection: out = (x@W + b) [*SCALE for Q], to [b,h,t,hd] bf16 -------
__global__ __launch_bounds__(256, 2) void qkv_gemm_kernel(
    const bf16* __restrict__ xb,
    const bf16* __restrict__ wqt, const bf16* __restrict__ wkt, const bf16* __restrict__ wvt,
    const float* __restrict__ bq, const float* __restrict__ bk, const float* __restrict__ bv,
    bf16* __restrict__ Qb, bf16* __restrict__ Kb, bf16* __restrict__ Vb) {
  const bf16* Bt; const float* bias; bf16* Out; float scale;
  int z = blockIdx.z;
  if (z == 0)      { Bt = wqt; bias = bq; Out = Qb; scale = SCALE_; }
  else if (z == 1) { Bt = wkt; bias = bk; Out = Kb; scale = 1.0f; }
  else             { Bt = wvt; bias = bv; Out = Vb; scale = 1.0f; }
  int m0 = blockIdx.y * 128, n0 = blockIdx.x * 128;
  f32x4 zero = {0.f, 0.f, 0.f, 0.f};
  f32x4 acc[4][4];
#pragma unroll
  for (int mi = 0; mi < 4; mi++)
#pragma unroll
    for (int ni = 0; ni < 4; ni++) acc[mi][ni] = zero;
  gemm_core_128(xb, Bt, acc, m0, n0);
  int lane = threadIdx.x & 63;
  int wr = (threadIdx.x >> 7) & 1, wc = (threadIdx.x >> 6) & 1;
#pragma unroll
  for (int ni = 0; ni < 4; ni++) {
    int cn = n0 + wc * 64 + ni * 16 + (lane & 15);
    float bb = bias[cn];
    int h = cn >> 7, hd = cn & 127;
#pragma unroll
    for (int mi = 0; mi < 4; mi++) {
      int rm = m0 + wr * 64 + mi * 16 + ((lane >> 4) << 2);
#pragma unroll
      for (int r = 0; r < 4; r++) {
        int mg = rm + r;
        int b = mg >> 11, tt = mg & 2047;
        Out[(size_t)((b * H_ + h) * T_ + tt) * HD_ + hd] = (bf16)((acc[mi][ni][r] + bb) * scale);
      }
    }
  }
}

// ------- V transpose: [bh][t][hd] -> [bh][hd][t] -------
__global__ void vtr_kernel(const bf16* __restrict__ V, bf16* __restrict__ Vt) {
  __shared__ bf16 tile[64][72];
  int t = threadIdx.x, tx = t & 15, ty = t >> 4;
  int t0 = blockIdx.x * 64, hd0 = blockIdx.y * 64, bh = blockIdx.z;
  const bf16* Vi = V + (size_t)bh * T_ * HD_;
  bf16* Vo = Vt + (size_t)bh * HD_ * T_;
#pragma unroll
  for (int i = 0; i < 4; i++) {
    bf16x4 v = *(const bf16x4*)&Vi[(size_t)(t0 + ty + i * 16) * HD_ + hd0 + tx * 4];
    tile[ty + i * 16][tx * 4 + 0] = v.x;
    tile[ty + i * 16][tx * 4 + 1] = v.y;
    tile[ty + i * 16][tx * 4 + 2] = v.z;
    tile[ty + i * 16][tx * 4 + 3] = v.w;
  }
  __syncthreads();
#pragma unroll
  for (int i = 0; i < 4; i++) {
    int hd = ty + i * 16;
    bf16x4 v;
    v.x = tile[tx * 4 + 0][hd];
    v.y = tile[tx * 4 + 1][hd];
    v.z = tile[tx * 4 + 2][hd];
    v.w = tile[tx * 4 + 3][hd];
    *(bf16x4*)&Vo[(size_t)(hd0 + hd) * T_ + t0 + tx * 4] = v;
  }
}

// ------- flash attention: per (bh, q-tile-of-128), TK=64, 4 waves x 32 q-rows -------
__global__ __launch_bounds__(256, 2) void attn_kernel(
    const bf16* __restrict__ Qb, const bf16* __restrict__ Kb,
    const bf16* __restrict__ Vtb, bf16* __restrict__ Ab) {
  __shared__ char smem[49152];
  char* Klds = smem;          // [64 tk][128 hd] bf16 swz (256B rows)
  char* Vlds = smem + 16384;  // [128 hd][64 tk] bf16 swz (128B rows)
  char* Plds = smem + 32768;  // [128 q][64 tk] bf16 swz (128B rows)
  const int t = threadIdx.x, lane = t & 63, w = t >> 6;
  const int bh = blockIdx.y;
  const int q0 = blockIdx.x * 128;
  const bf16* Qh = Qb + (size_t)bh * T_ * HD_;
  const bf16* Kh = Kb + (size_t)bh * T_ * HD_;
  const bf16* Vh = Vtb + (size_t)bh * HD_ * T_;

  // Q fragments live in registers across all KV tiles (SCALE pre-folded)
  bf16x8 qf[2][4];
#pragma unroll
  for (int mi = 0; mi < 2; mi++)
#pragma unroll
    for (int kf = 0; kf < 4; kf++) {
      int row = q0 + w * 32 + mi * 16 + (lane & 15);
      int hd = kf * 32 + ((lane >> 4) << 3);
      qf[mi][kf] = *(const bf16x8*)(Qh + (size_t)row * HD_ + hd);
    }

  f32x4 zero = {0.f, 0.f, 0.f, 0.f};
  f32x4 o[2][8];
#pragma unroll
  for (int mi = 0; mi < 2; mi++)
#pragma unroll
    for (int nf = 0; nf < 8; nf++) o[mi][nf] = zero;
  float mrow[2][4], lrow[2][4];
#pragma unroll
  for (int mi = 0; mi < 2; mi++)
#pragma unroll
    for (int r = 0; r < 4; r++) { mrow[mi][r] = -1e30f; lrow[mi][r] = 0.f; }

  for (int kt = 0; kt < T_; kt += 64) {
#pragma unroll
    for (int i = 0; i < 4; i++) {
      int L = i * 4096 + t * 16;
      int rowK = L >> 8;
      int kbK = (L & 255) ^ ((rowK & 7) << 4);
      gload_lds16(Kh + (size_t)(kt + rowK) * HD_ + (kbK >> 1), Klds + L);
      int rowV = L >> 7;
      int kbV = (L & 127) ^ ((rowV & 7) << 4);
      gload_lds16(Vh + (size_t)rowV * T_ + kt + (kbV >> 1), Vlds + L);
    }
    __syncthreads();

    // S[q][tk] = Q K^T  (Q pre-scaled)
    f32x4 s[2][4];
#pragma unroll
    for (int mi = 0; mi < 2; mi++)
#pragma unroll
      for (int nf = 0; nf < 4; nf++) s[mi][nf] = zero;
#pragma unroll
    for (int kf = 0; kf < 4; kf++) {
      int kb = kf * 64 + ((lane >> 4) << 4);
      bf16x8 kfr[4];
#pragma unroll
      for (int nf = 0; nf < 4; nf++) {
        int rr = nf * 16 + (lane & 15);
        kfr[nf] = *(const bf16x8*)(Klds + rr * 256 + (kb ^ ((rr & 7) << 4)));
      }
#pragma unroll
      for (int mi = 0; mi < 2; mi++)
#pragma unroll
        for (int nf = 0; nf < 4; nf++)
          s[mi][nf] = __builtin_amdgcn_mfma_f32_16x16x32_bf16(qf[mi][kf], kfr[nf], s[mi][nf], 0, 0, 0);
    }

    // online softmax (row spread over 16 lanes of same l>>4 group)
#pragma unroll
    for (int mi = 0; mi < 2; mi++) {
#pragma unroll
      for (int r = 0; r < 4; r++) {
        float mx = fmaxf(fmaxf(s[mi][0][r], s[mi][1][r]), fmaxf(s[mi][2][r], s[mi][3][r]));
        mx = fmaxf(mx, __shfl_xor(mx, 1));
        mx = fmaxf(mx, __shfl_xor(mx, 2));
        mx = fmaxf(mx, __shfl_xor(mx, 4));
        mx = fmaxf(mx, __shfl_xor(mx, 8));
        float mnew = fmaxf(mrow[mi][r], mx);
        float fac = __expf(mrow[mi][r] - mnew);
        mrow[mi][r] = mnew;
        float rs = 0.f;
#pragma unroll
        for (int nf = 0; nf < 4; nf++) {
          float p = __expf(s[mi][nf][r] - mnew);
          s[mi][nf][r] = p;
          rs += p;
        }
        rs += __shfl_xor(rs, 1);
        rs += __shfl_xor(rs, 2);
        rs += __shfl_xor(rs, 4);
        rs += __shfl_xor(rs, 8);
        lrow[mi][r] = lrow[mi][r] * fac + rs;
#pragma unroll
        for (int nf = 0; nf < 8; nf++) o[mi][nf][r] *= fac;
        // P -> LDS (wave-local rows; no barrier needed before PV)
        int row = w * 32 + mi * 16 + ((lane >> 4) << 2) + r;
#pragma unroll
        for (int nf = 0; nf < 4; nf++) {
          int cb = (nf * 32 + (lane & 15) * 2) ^ ((row & 7) << 4);
          *(bf16*)(Plds + row * 128 + cb) = (bf16)s[mi][nf][r];
        }
      }
    }

    // O += P V
#pragma unroll
    for (int kf = 0; kf < 2; kf++) {
      int kb = kf * 64 + ((lane >> 4) << 4);
      bf16x8 pf[2];
#pragma unroll
      for (int mi = 0; mi < 2; mi++) {
        int rr = w * 32 + mi * 16 + (lane & 15);
        pf[mi] = *(const bf16x8*)(Plds + rr * 128 + (kb ^ ((rr & 7) << 4)));
      }
#pragma unroll
      for (int nf = 0; nf < 8; nf++) {
        int rr = nf * 16 + (lane & 15);
        bf16x8 vf = *(const bf16x8*)(Vlds + rr * 128 + (kb ^ ((rr & 7) << 4)));
#pragma unroll
        for (int mi = 0; mi < 2; mi++)
          o[mi][nf] = __builtin_amdgcn_mfma_f32_16x16x32_bf16(pf[mi], vf, o[mi][nf], 0, 0, 0);
      }
    }
    __syncthreads();  // K/V/P LDS free for next tile
  }

  // normalize + write attn out as [token][h*128+hd] bf16
  int b = bh >> 4, h = bh & 15;
#pragma unroll
  for (int mi = 0; mi < 2; mi++)
#pragma unroll
    for (int r = 0; r < 4; r++) {
      float inv = 1.f / lrow[mi][r];
      int tq = q0 + w * 32 + mi * 16 + ((lane >> 4) << 2) + r;
      size_t base = ((size_t)b * T_ + tq) * D_ + h * HD_;
#pragma unroll
      for (int nf = 0; nf < 8; nf++) {
        int hd = nf * 16 + (lane & 15);
        Ab[base + hd] = (bf16)(o[mi][nf][r] * inv);
      }
    }
}

// ------- output projection: out = attn @ wo + bo (fp32 out) -------
__global__ __launch_bounds__(256, 2) void out_gemm_kernel(
    const bf16* __restrict__ Ab, const bf16* __restrict__ wot,
    const float* __restrict__ bo, float* __restrict__ out) {
  int m0 = blockIdx.y * 128, n0 = blockIdx.x * 128;
  f32x4 zero = {0.f, 0.f, 0.f, 0.f};
  f32x4 acc[4][4];
#pragma unroll
  for (int mi = 0; mi < 4; mi++)
#pragma unroll
    for (int ni = 0; ni < 4; ni++) acc[mi][ni] = zero;
  gemm_core_128(Ab, wot, acc, m0, n0);
  int lane = threadIdx.x & 63;
  int wr = (threadIdx.x >> 7) & 1, wc = (threadIdx.x >> 6) & 1;
#pragma unroll
  for (int ni = 0; ni < 4; ni++) {
    int cn = n0 + wc * 64 + ni * 16 + (lane & 15);
    float bb = bo[cn];
#pragma unroll
    for (int mi = 0; mi < 4; mi++) {
      int rm = m0 + wr * 64 + mi * 16 + ((lane >> 4) << 2);
#pragma unroll
      for (int r = 0; r < 4; r++)
        out[(size_t)(rm + r) * D_ + cn] = acc[mi][ni][r] + bb;
    }
  }
}

extern "C" void kernel_launch(void* const* d_in, const int* in_sizes, int n_in,
                              void* d_out, int out_size, void* d_ws, size_t ws_size,
                              hipStream_t stream) {
  const float* x  = (const float*)d_in[0];
  const float* wq = (const float*)d_in[1];
  const float* bq = (const float*)d_in[2];
  const float* wk = (const float*)d_in[3];
  const float* bk = (const float*)d_in[4];
  const float* wv = (const float*)d_in[5];
  const float* bv = (const float*)d_in[6];
  const float* wo = (const float*)d_in[7];
  const float* bo = (const float*)d_in[8];
  float* out = (float*)d_out;
  char* ws = (char*)d_ws;

  bf16* xb  = (bf16*)(ws);               // 16 MB  [4096][2048]
  bf16* wqt = (bf16*)(ws + 16777216);    // 8 MB   [n][k]
  bf16* wkt = (bf16*)(ws + 25165824);
  bf16* wvt = (bf16*)(ws + 33554432);
  bf16* wot = (bf16*)(ws + 41943040);
  bf16* Qb  = (bf16*)(ws + 50331648);    // 16 MB  [bh][t][hd] (pre-scaled)
  bf16* Kb  = (bf16*)(ws + 67108864);    // 16 MB  [bh][t][hd]
  bf16* Vb  = (bf16*)(ws + 83886080);    // 16 MB  [bh][t][hd]
  bf16* Vtb = (bf16*)(ws + 100663296);   // 16 MB  [bh][hd][t]
  bf16* Ab  = xb;  // xb dead after qkv_gemm; reuse for attention output

  cast_x_kernel<<<8192, 256, 0, stream>>>(x, xb);
  twcast_kernel<<<dim3(32, 32, 4), 256, 0, stream>>>(wq, wk, wv, wo, wqt, wkt, wvt, wot);
  qkv_gemm_kernel<<<dim3(16, 32, 3), 256, 0, stream>>>(xb, wqt, wkt, wvt, bq, bk, bv, Qb, Kb, Vb);
  vtr_kernel<<<dim3(32, 2, 32), 256, 0, stream>>>(Vb, Vtb);
  attn_kernel<<<dim3(16, 32), 256, 0, stream>>>(Qb, Kb, Vtb, Ab);
  out_gemm_kernel<<<dim3(16, 32), 256, 0, stream>>>(Ab, wot, bo, out);

  (void)in_sizes; (void)n_in; (void)out_size; (void)ws_size;
}